// Round 1
// baseline (1290.858 us; speedup 1.0000x reference)
//
#include <hip/hip_runtime.h>
#include <math.h>
#include <stdint.h>

#define DIM   64
#define KNB   16
#define PH    64
#define AH    256
#define QKVW  192   // 3*DIM

// ---------------------------------------------------------------------------
// Kernel 1: qkv = x @ w_qkv   [N,64] @ [64,192] -> [N,192]
// One thread per output element; x-row reads are L1-broadcast, w columns
// coalesced across lanes.
// ---------------------------------------------------------------------------
__global__ __launch_bounds__(256) void qkv_kernel(const float* __restrict__ x,
                                                  const float* __restrict__ w,
                                                  float* __restrict__ qkv,
                                                  int total) {
    long id = (long)blockIdx.x * blockDim.x + threadIdx.x;
    if (id >= total) return;
    int row = (int)(id / QKVW);
    int col = (int)(id - (long)row * QKVW);
    const float* xr = x + (long)row * DIM;
    float acc = 0.f;
#pragma unroll
    for (int d = 0; d < DIM; ++d) acc = fmaf(xr[d], w[d * QKVW + col], acc);
    qkv[id] = acc;
}

// ---------------------------------------------------------------------------
// Kernel 2: the whole layer, one block (256 threads) per point.
//   step2: h1 = relu(rel_pos @ pm_w1 + b1)           -> s_h1T [64][20]
//   step3: rel = h1 @ pm_w2 + b2                     -> s_rel [16][64]
//   step4: t = k_j - q + rel ; vrel = v_j + rel      -> s_tT  [64][20]
//   step5: h2 = relu(t @ am_w1 + b1)                 -> s_h2T [256][20]
//   step6: w  = h2 @ am_w2 + b2                      -> s_w   [16][64]
//   step7: per-channel softmax over K + aggregation  -> out
// Transposed LDS tiles padded to 20 floats/row: 16B-aligned float4 rows,
// write conflicts capped at ~8-way (one-time per step, BW-floor anyway).
// FUSE=1 computes q/k/v in-kernel (no workspace needed).
// ---------------------------------------------------------------------------
template <int FUSE>
__global__ __launch_bounds__(256, 3) void ptl_main(
    const float* __restrict__ x,          // only used when FUSE=1
    const float* __restrict__ w_qkv,      // only used when FUSE=1
    const float* __restrict__ pos,
    const int* __restrict__ aidx,
    const uint8_t* __restrict__ mask,
    const float* __restrict__ pm_w1, const float* __restrict__ pm_b1,
    const float* __restrict__ pm_w2, const float* __restrict__ pm_b2,
    const float* __restrict__ am_w1, const float* __restrict__ am_b1,
    const float* __restrict__ am_w2, const float* __restrict__ am_b2,
    const float* __restrict__ qkv,        // only used when FUSE=0
    float* __restrict__ out)
{
    const int i   = blockIdx.x;
    const int tid = threadIdx.x;
    const int c   = tid & 63;   // channel lane
    const int kg  = tid >> 6;   // neighbor-quad group 0..3

    __shared__ alignas(16) float s_q[DIM];
    __shared__ alignas(16) float s_xq[DIM];          // FUSE only
    __shared__ alignas(16) float s_xn[KNB][DIM];     // FUSE only
    __shared__ int               s_idx[KNB];
    __shared__ alignas(16) float s_rp[KNB][4];
    __shared__ alignas(16) float s_h1T[PH][20];
    __shared__ alignas(16) float s_rel[KNB][DIM];
    __shared__ alignas(16) float s_tT[DIM][20];
    __shared__ alignas(16) float s_vrel[KNB][DIM];
    __shared__ alignas(16) float s_h2T[AH][20];
    __shared__ alignas(16) float s_w[KNB][DIM];

    // ---- load indices, q (or x_i), rel_pos --------------------------------
    if (tid < KNB) s_idx[tid] = aidx[i * KNB + tid];
    if (FUSE) {
        if (tid < DIM) s_xq[tid] = x[(long)i * DIM + tid];
    } else {
        if (tid < DIM) s_q[tid] = qkv[(long)i * QKVW + tid];
    }
    __syncthreads();

    if (tid < 48) {
        int k = tid / 3, a = tid - 3 * k;
        s_rp[k][a] = pos[(long)s_idx[k] * 3 + a] - pos[(long)i * 3 + a];
    }
    if (FUSE) {
        // stage neighbor x rows
#pragma unroll
        for (int kk = 0; kk < 4; ++kk) {
            int k = kg * 4 + kk;
            s_xn[k][c] = x[(long)s_idx[k] * DIM + c];
        }
    }
    __syncthreads();

    if (FUSE) {
        // q[c] = x_i . w_qkv[:, c]  (wave 0 only)
        if (tid < DIM) {
            float acc = 0.f;
#pragma unroll
            for (int d = 0; d < DIM; ++d)
                acc = fmaf(s_xq[d], w_qkv[d * QKVW + tid], acc);
            s_q[tid] = acc;
        }
    }

    // ---- step2: h1T[p][k] = relu(rp[k] . pm_w1[:,p] + b1[p]) --------------
    {
        float b  = pm_b1[c];
        float w0 = pm_w1[0 * PH + c], w1 = pm_w1[1 * PH + c], w2 = pm_w1[2 * PH + c];
#pragma unroll
        for (int kk = 0; kk < 4; ++kk) {
            int k = kg * 4 + kk;
            float acc = b + s_rp[k][0] * w0 + s_rp[k][1] * w1 + s_rp[k][2] * w2;
            s_h1T[c][k] = fmaxf(acc, 0.f);
        }
    }
    __syncthreads();

    // ---- step3: rel[k][c] = h1[k] . pm_w2[:,c] + b2[c] --------------------
    {
        float a0 = 0.f, a1 = 0.f, a2 = 0.f, a3 = 0.f;
        for (int p = 0; p < PH; ++p) {
            const float4 h = *(const float4*)&s_h1T[p][kg * 4];
            const float wv = pm_w2[p * DIM + c];
            a0 = fmaf(h.x, wv, a0);
            a1 = fmaf(h.y, wv, a1);
            a2 = fmaf(h.z, wv, a2);
            a3 = fmaf(h.w, wv, a3);
        }
        const float b = pm_b2[c];
        s_rel[kg * 4 + 0][c] = a0 + b;
        s_rel[kg * 4 + 1][c] = a1 + b;
        s_rel[kg * 4 + 2][c] = a2 + b;
        s_rel[kg * 4 + 3][c] = a3 + b;
    }
    __syncthreads();

    // ---- step4: tT[c][k] = k_j[c] - q[c] + rel ; vrel = v_j[c] + rel ------
    {
#pragma unroll
        for (int kk = 0; kk < 4; ++kk) {
            int k = kg * 4 + kk;
            float kj, vj;
            if (FUSE) {
                float ka = 0.f, va = 0.f;
#pragma unroll
                for (int d = 0; d < DIM; ++d) {
                    const float xv = s_xn[k][d];
                    ka = fmaf(xv, w_qkv[d * QKVW + DIM + c], ka);
                    va = fmaf(xv, w_qkv[d * QKVW + 2 * DIM + c], va);
                }
                kj = ka; vj = va;
            } else {
                long base = (long)s_idx[k] * QKVW;
                kj = qkv[base + DIM + c];
                vj = qkv[base + 2 * DIM + c];
            }
            const float r = s_rel[k][c];
            s_tT[c][k]   = kj - s_q[c] + r;
            s_vrel[k][c] = vj + r;
        }
    }
    __syncthreads();

    // ---- step5: h2T[h][k] = relu(t[k] . am_w1[:,h] + b1[h]), h = tid ------
    {
        float h2acc[KNB];
        const float b = am_b1[tid];
#pragma unroll
        for (int k = 0; k < KNB; ++k) h2acc[k] = b;
        for (int d = 0; d < DIM; ++d) {
            float tv[KNB];
            *(float4*)(&tv[0])  = *(const float4*)(&s_tT[d][0]);
            *(float4*)(&tv[4])  = *(const float4*)(&s_tT[d][4]);
            *(float4*)(&tv[8])  = *(const float4*)(&s_tT[d][8]);
            *(float4*)(&tv[12]) = *(const float4*)(&s_tT[d][12]);
            const float wv = am_w1[d * AH + tid];
#pragma unroll
            for (int k = 0; k < KNB; ++k) h2acc[k] = fmaf(tv[k], wv, h2acc[k]);
        }
        float4 o;
        o.x = fmaxf(h2acc[0], 0.f); o.y = fmaxf(h2acc[1], 0.f);
        o.z = fmaxf(h2acc[2], 0.f); o.w = fmaxf(h2acc[3], 0.f);
        *(float4*)&s_h2T[tid][0] = o;
        o.x = fmaxf(h2acc[4], 0.f); o.y = fmaxf(h2acc[5], 0.f);
        o.z = fmaxf(h2acc[6], 0.f); o.w = fmaxf(h2acc[7], 0.f);
        *(float4*)&s_h2T[tid][4] = o;
        o.x = fmaxf(h2acc[8], 0.f); o.y = fmaxf(h2acc[9], 0.f);
        o.z = fmaxf(h2acc[10], 0.f); o.w = fmaxf(h2acc[11], 0.f);
        *(float4*)&s_h2T[tid][8] = o;
        o.x = fmaxf(h2acc[12], 0.f); o.y = fmaxf(h2acc[13], 0.f);
        o.z = fmaxf(h2acc[14], 0.f); o.w = fmaxf(h2acc[15], 0.f);
        *(float4*)&s_h2T[tid][12] = o;
    }
    __syncthreads();

    // ---- step6: w[k][c] = h2[k] . am_w2[:,c] + b2[c] ----------------------
    {
        float a0 = 0.f, a1 = 0.f, a2 = 0.f, a3 = 0.f;
        for (int h = 0; h < AH; ++h) {
            const float4 hv = *(const float4*)&s_h2T[h][kg * 4];
            const float wv = am_w2[h * DIM + c];
            a0 = fmaf(hv.x, wv, a0);
            a1 = fmaf(hv.y, wv, a1);
            a2 = fmaf(hv.z, wv, a2);
            a3 = fmaf(hv.w, wv, a3);
        }
        const float b = am_b2[c];
        s_w[kg * 4 + 0][c] = a0 + b;
        s_w[kg * 4 + 1][c] = a1 + b;
        s_w[kg * 4 + 2][c] = a2 + b;
        s_w[kg * 4 + 3][c] = a3 + b;
    }
    __syncthreads();

    // ---- step7: per-channel masked softmax over K + aggregate -------------
    if (tid < DIM) {
        float vals[KNB];
        float m = -INFINITY;
#pragma unroll
        for (int k = 0; k < KNB; ++k) {
            float v = s_w[k][tid];
            if (mask[i * KNB + k] != 0) v = -INFINITY;
            vals[k] = v;
            m = fmaxf(m, v);
        }
        float S = 0.f;
#pragma unroll
        for (int k = 0; k < KNB; ++k) {
            float e = expf(vals[k] - m);
            vals[k] = e;
            S += e;
        }
        const float inv = 1.0f / S;
        float acc = 0.f;
#pragma unroll
        for (int k = 0; k < KNB; ++k) acc = fmaf(s_vrel[k][tid], vals[k], acc);
        out[(long)i * DIM + tid] = acc * inv;
    }
}

// ---------------------------------------------------------------------------
extern "C" void kernel_launch(void* const* d_in, const int* in_sizes, int n_in,
                              void* d_out, int out_size, void* d_ws, size_t ws_size,
                              hipStream_t stream) {
    const float*   x      = (const float*)d_in[0];
    const float*   pos    = (const float*)d_in[1];
    const int*     aidx   = (const int*)d_in[2];
    const uint8_t* mask   = (const uint8_t*)d_in[3];
    const float*   w_qkv  = (const float*)d_in[4];
    const float*   pm_w1  = (const float*)d_in[5];
    const float*   pm_b1  = (const float*)d_in[6];
    const float*   pm_w2  = (const float*)d_in[7];
    const float*   pm_b2  = (const float*)d_in[8];
    const float*   am_w1  = (const float*)d_in[9];
    const float*   am_b1  = (const float*)d_in[10];
    const float*   am_w2  = (const float*)d_in[11];
    const float*   am_b2  = (const float*)d_in[12];
    float*         out    = (float*)d_out;

    const int n = in_sizes[0] / DIM;           // 50000
    const size_t qkv_bytes = (size_t)n * QKVW * sizeof(float);

    if (ws_size >= qkv_bytes) {
        float* qkv = (float*)d_ws;
        const int total = n * QKVW;
        qkv_kernel<<<(total + 255) / 256, 256, 0, stream>>>(x, w_qkv, qkv, total);
        ptl_main<0><<<n, 256, 0, stream>>>(x, w_qkv, pos, aidx, mask,
                                           pm_w1, pm_b1, pm_w2, pm_b2,
                                           am_w1, am_b1, am_w2, am_b2,
                                           qkv, out);
    } else {
        // workspace too small: fused q/k/v recompute inside the main kernel
        ptl_main<1><<<n, 256, 0, stream>>>(x, w_qkv, pos, aidx, mask,
                                           pm_w1, pm_b1, pm_w2, pm_b2,
                                           am_w1, am_b1, am_w2, am_b2,
                                           nullptr, out);
    }
}

// Round 3
// 426.480 us; speedup vs baseline: 3.0268x; 3.0268x over previous
//
#include <hip/hip_runtime.h>
#include <math.h>
#include <stdint.h>

#define DIM  64
#define KNB  16
#define QKVW 192

typedef short bf16x8 __attribute__((ext_vector_type(8)));
typedef float f32x4  __attribute__((ext_vector_type(4)));

__device__ __forceinline__ uint16_t f2bf(float x) {
    uint32_t u = __builtin_bit_cast(uint32_t, x);
    u += 0x7fffu + ((u >> 16) & 1u);          // RNE
    return (uint16_t)(u >> 16);
}
__device__ __forceinline__ float bf2f(uint16_t u) {
    uint32_t v = ((uint32_t)u) << 16;
    return __builtin_bit_cast(float, v);
}

// ---------------------------------------------------------------------------
// qkv = x @ w_qkv -> q (f32 [N][64]) + kv (bf16 [N][128], k then v)
// 4 output cols per thread.
// ---------------------------------------------------------------------------
__global__ __launch_bounds__(256) void qkv_kernel(
    const float* __restrict__ x, const float* __restrict__ wqkv,
    float* __restrict__ qf, uint16_t* __restrict__ kvp, int n)
{
    int id  = blockIdx.x * 256 + threadIdx.x;
    int row = id / 48;
    int c0  = (id - row * 48) * 4;
    if (row >= n) return;
    const float* xr = x + (size_t)row * DIM;
    float4 acc = {0.f, 0.f, 0.f, 0.f};
#pragma unroll
    for (int d = 0; d < DIM; ++d) {
        float xv = xr[d];
        const float4 wv = *(const float4*)(wqkv + d * QKVW + c0);
        acc.x = fmaf(xv, wv.x, acc.x);
        acc.y = fmaf(xv, wv.y, acc.y);
        acc.z = fmaf(xv, wv.z, acc.z);
        acc.w = fmaf(xv, wv.w, acc.w);
    }
    if (c0 < 64) {
        *(float4*)(qf + (size_t)row * 64 + c0) = acc;
    } else {
        int c = c0 - 64;
        uint32_t lo = (uint32_t)f2bf(acc.x) | ((uint32_t)f2bf(acc.y) << 16);
        uint32_t hi = (uint32_t)f2bf(acc.z) | ((uint32_t)f2bf(acc.w) << 16);
        *(uint2*)(kvp + (size_t)row * 128 + c) = make_uint2(lo, hi);
    }
}

// ---------------------------------------------------------------------------
// Prepack am_w1 / am_w2 / pm_w2 into bf16 MFMA fragment order.
// Fragment convention (16x16x32): non-K index = lane&15, K = 32*kt + 8*(lane>>4) + j.
// w1p : A-frags of am_w1^T  (M=256 hidden, K=64)   [mt 0..15][kt 0..1]
// w2p : A-frags of am_w2^T  (M=64 out,     K=256)  [mt 0..3 ][kt 0..7]
// pw2p: B-frags of pm_w2    (K=64 hidden,  N=64)   [nt 0..3 ][kt 0..1]
// ---------------------------------------------------------------------------
__global__ __launch_bounds__(256) void wpack_kernel(
    const float* __restrict__ am_w1, const float* __restrict__ am_w2,
    const float* __restrict__ pm_w2,
    uint16_t* __restrict__ w1p, uint16_t* __restrict__ w2p, uint16_t* __restrict__ pw2p)
{
    int t = blockIdx.x * 256 + threadIdx.x;
    if (t >= 36864) return;
    int j = t & 7, lane = (t >> 3) & 63, tile = t >> 9;
    int g = lane >> 4, nb = lane & 15;
    if (tile < 32) {
        int mt = tile >> 1, kt = tile & 1;
        w1p[t] = f2bf(am_w1[(32*kt + 8*g + j) * 256 + 16*mt + nb]);
    } else if (tile < 64) {
        int tt = tile - 32;
        int mt = tt >> 3, kt = tt & 7;
        w2p[t - 16384] = f2bf(am_w2[(32*kt + 8*g + j) * 64 + 16*mt + nb]);
    } else {
        int tt = tile - 64;
        int nt = tt >> 1, kt = tt & 1;
        pw2p[t - 32768] = f2bf(pm_w2[(32*kt + 8*g + j) * 64 + 16*nt + nb]);
    }
}

// ---------------------------------------------------------------------------
// Main: block = 4 waves, grid-strides over points; weights register-resident.
// Per point: wave w owns rel dim-tile w, hidden slice [64w,64w+64), out tile w.
// LDS (double-buffered, XOR-swizzled): s_rel f32[16][64], s_h2 bf16[16][256].
// 2 barriers / point.
// ---------------------------------------------------------------------------
__global__ __launch_bounds__(256, 2) void ptl_main(
    const float* __restrict__ pos,
    const int* __restrict__ aidx,
    const uint8_t* __restrict__ mask,
    const float* __restrict__ pm_w1,
    const float* __restrict__ pm_b1,
    const float* __restrict__ pm_b2,
    const float* __restrict__ am_b1,
    const float* __restrict__ qf,
    const uint16_t* __restrict__ kvp,
    const uint16_t* __restrict__ w1p,
    const uint16_t* __restrict__ w2p,
    const uint16_t* __restrict__ pw2p,
    float* __restrict__ out,
    int npts)
{
    const int tid  = threadIdx.x;
    const int w    = tid >> 6;
    const int lane = tid & 63;
    const int g    = lane >> 4;
    const int nb   = lane & 15;
    const int swz  = 16 * (nb & 7);

    __shared__ float    s_rel[2][1024];   // [16 rows][64 f32] swizzled
    __shared__ uint16_t s_h2[2][4096];    // [16 rows][256 bf16] swizzled

    // register-resident weight fragments (72 VGPR)
    bf16x8 aw1[4][2], aw2[8], bpw2[2];
#pragma unroll
    for (int m = 0; m < 4; ++m)
#pragma unroll
        for (int kt = 0; kt < 2; ++kt)
            aw1[m][kt] = *(const bf16x8*)(w1p + (size_t)(((4*w + m)*2 + kt)*64 + lane) * 8);
#pragma unroll
    for (int kt = 0; kt < 8; ++kt)
        aw2[kt] = *(const bf16x8*)(w2p + (size_t)((w*8 + kt)*64 + lane) * 8);
#pragma unroll
    for (int kt = 0; kt < 2; ++kt)
        bpw2[kt] = *(const bf16x8*)(pw2p + (size_t)((w*2 + kt)*64 + lane) * 8);

    int buf = 0;
    for (int i = blockIdx.x; i < npts; i += gridDim.x, buf ^= 1) {
        const int nidx = aidx[i * KNB + nb];
        const float rx = pos[3*nidx]     - pos[3*i];
        const float ry = pos[3*nidx + 1] - pos[3*i + 1];
        const float rz = pos[3*nidx + 2] - pos[3*i + 2];

        // ---- pos-MLP layer 1 -> h1 A-frags (lane: row nb, k = 32kt+8g+j) ----
        bf16x8 h1f[2];
#pragma unroll
        for (int kt = 0; kt < 2; ++kt) {
            const int hb = 32*kt + 8*g;
            float w0[8], w1r[8], w2r[8], bb[8];
            *(float4*)&w0[0]  = *(const float4*)(pm_w1 + hb);
            *(float4*)&w0[4]  = *(const float4*)(pm_w1 + hb + 4);
            *(float4*)&w1r[0] = *(const float4*)(pm_w1 + 64 + hb);
            *(float4*)&w1r[4] = *(const float4*)(pm_w1 + 64 + hb + 4);
            *(float4*)&w2r[0] = *(const float4*)(pm_w1 + 128 + hb);
            *(float4*)&w2r[4] = *(const float4*)(pm_w1 + 128 + hb + 4);
            *(float4*)&bb[0]  = *(const float4*)(pm_b1 + hb);
            *(float4*)&bb[4]  = *(const float4*)(pm_b1 + hb + 4);
            bf16x8 f;
#pragma unroll
            for (int jj = 0; jj < 8; ++jj) {
                float v = fmaf(rx, w0[jj], fmaf(ry, w1r[jj], fmaf(rz, w2r[jj], bb[jj])));
                f[jj] = (short)f2bf(fmaxf(v, 0.f));
            }
            h1f[kt] = f;
        }

        // ---- rel tile (nt = w): rel = h1 @ pm_w2 + pm_b2 ----
        f32x4 racc = {0.f, 0.f, 0.f, 0.f};
        racc = __builtin_amdgcn_mfma_f32_16x16x32_bf16(h1f[0], bpw2[0], racc, 0, 0, 0);
        racc = __builtin_amdgcn_mfma_f32_16x16x32_bf16(h1f[1], bpw2[1], racc, 0, 0, 0);
        {
            const float pb2 = pm_b2[16*w + nb];
#pragma unroll
            for (int r = 0; r < 4; ++r) {
                const int row = 4*g + r;   // neighbor
                s_rel[buf][(row*256 + ((4*(16*w + nb)) ^ (16*(row & 7)))) >> 2] = racc[r] + pb2;
            }
        }
        __syncthreads();

        // ---- t = k - q + rel -> B-frags (lane: col nb, k = 32kt+8g+j) ----
        const uint16_t* kvrow = kvp + (size_t)nidx * 128;
        bf16x8 tf[2];
#pragma unroll
        for (int kt = 0; kt < 2; ++kt) {
            const int db = 32*kt + 8*g;
            const bf16x8 kv8 = *(const bf16x8*)(kvrow + db);
            const float4 q0 = *(const float4*)(qf + (size_t)i*64 + db);
            const float4 q1 = *(const float4*)(qf + (size_t)i*64 + db + 4);
            const float4 rl0 = *(const float4*)&s_rel[buf][(nb*256 + ((128*kt + 32*g) ^ swz)) >> 2];
            const float4 rl1 = *(const float4*)&s_rel[buf][(nb*256 + ((128*kt + 32*g + 16) ^ swz)) >> 2];
            float qv[8] = {q0.x, q0.y, q0.z, q0.w, q1.x, q1.y, q1.z, q1.w};
            float rv[8] = {rl0.x, rl0.y, rl0.z, rl0.w, rl1.x, rl1.y, rl1.z, rl1.w};
            bf16x8 f;
#pragma unroll
            for (int jj = 0; jj < 8; ++jj)
                f[jj] = (short)f2bf(bf2f((uint16_t)kv8[jj]) - qv[jj] + rv[jj]);
            tf[kt] = f;
        }

        // ---- step5: h2^T slice = w1^T @ t^T  (hidden 16*(4w+m)+4g+r) ----
        f32x4 hacc[4];
#pragma unroll
        for (int m = 0; m < 4; ++m) {
            f32x4 a = {0.f, 0.f, 0.f, 0.f};
            a = __builtin_amdgcn_mfma_f32_16x16x32_bf16(aw1[m][0], tf[0], a, 0, 0, 0);
            a = __builtin_amdgcn_mfma_f32_16x16x32_bf16(aw1[m][1], tf[1], a, 0, 0, 0);
            hacc[m] = a;
        }
#pragma unroll
        for (int m = 0; m < 4; ++m) {
            const int hb = 16*(4*w + m) + 4*g;
            const float4 b4 = *(const float4*)(am_b1 + hb);
            const uint32_t lo = (uint32_t)f2bf(fmaxf(hacc[m][0] + b4.x, 0.f))
                              | ((uint32_t)f2bf(fmaxf(hacc[m][1] + b4.y, 0.f)) << 16);
            const uint32_t hi = (uint32_t)f2bf(fmaxf(hacc[m][2] + b4.z, 0.f))
                              | ((uint32_t)f2bf(fmaxf(hacc[m][3] + b4.w, 0.f)) << 16);
            *(uint2*)&s_h2[buf][(nb*512 + ((2*hb) ^ swz)) >> 1] = make_uint2(lo, hi);
        }
        __syncthreads();

        // ---- step6: w^T tile w = w2^T @ h2^T ----
        f32x4 wacc = {0.f, 0.f, 0.f, 0.f};
#pragma unroll
        for (int kt = 0; kt < 8; ++kt) {
            const bf16x8 bh2 = *(const bf16x8*)&s_h2[buf][(nb*512 + ((64*kt + 16*g) ^ swz)) >> 1];
            wacc = __builtin_amdgcn_mfma_f32_16x16x32_bf16(aw2[kt], bh2, wacc, 0, 0, 0);
        }

        // ---- masked softmax over neighbors (16 lanes) + aggregation ----
        const bool msk = mask[i * KNB + nb] != 0;
        float e0 = msk ? -INFINITY : wacc[0];
        float e1 = msk ? -INFINITY : wacc[1];
        float e2 = msk ? -INFINITY : wacc[2];
        float e3 = msk ? -INFINITY : wacc[3];
        float m0 = e0, m1 = e1, m2 = e2, m3 = e3;
#pragma unroll
        for (int s = 1; s < 16; s <<= 1) {
            m0 = fmaxf(m0, __shfl_xor(m0, s));
            m1 = fmaxf(m1, __shfl_xor(m1, s));
            m2 = fmaxf(m2, __shfl_xor(m2, s));
            m3 = fmaxf(m3, __shfl_xor(m3, s));
        }
        e0 = __expf(e0 - m0); e1 = __expf(e1 - m1);
        e2 = __expf(e2 - m2); e3 = __expf(e3 - m3);

        const float4 rl = *(const float4*)&s_rel[buf][(nb*256 + ((4*(16*w + 4*g)) ^ swz)) >> 2];
        const uint2 vv = *(const uint2*)(kvrow + 64 + 16*w + 4*g);
        float n0 = e0 * (bf2f((uint16_t)(vv.x & 0xffffu)) + rl.x);
        float n1 = e1 * (bf2f((uint16_t)(vv.x >> 16))     + rl.y);
        float n2 = e2 * (bf2f((uint16_t)(vv.y & 0xffffu)) + rl.z);
        float n3 = e3 * (bf2f((uint16_t)(vv.y >> 16))     + rl.w);
#pragma unroll
        for (int s = 1; s < 16; s <<= 1) {
            n0 += __shfl_xor(n0, s); e0 += __shfl_xor(e0, s);
            n1 += __shfl_xor(n1, s); e1 += __shfl_xor(e1, s);
            n2 += __shfl_xor(n2, s); e2 += __shfl_xor(e2, s);
            n3 += __shfl_xor(n3, s); e3 += __shfl_xor(e3, s);
        }
        if (nb == 0) {
            float4 o = {n0 / e0, n1 / e1, n2 / e2, n3 / e3};
            *(float4*)(out + (size_t)i*64 + 16*w + 4*g) = o;
        }
        // no trailing barrier needed: double-buffered LDS + 2 barriers/iter
    }
}

// ---------------------------------------------------------------------------
extern "C" void kernel_launch(void* const* d_in, const int* in_sizes, int n_in,
                              void* d_out, int out_size, void* d_ws, size_t ws_size,
                              hipStream_t stream) {
    const float*   x     = (const float*)d_in[0];
    const float*   pos   = (const float*)d_in[1];
    const int*     aidx  = (const int*)d_in[2];
    const uint8_t* mask  = (const uint8_t*)d_in[3];
    const float*   wqkv  = (const float*)d_in[4];
    const float*   pm_w1 = (const float*)d_in[5];
    const float*   pm_b1 = (const float*)d_in[6];
    const float*   pm_w2 = (const float*)d_in[7];
    const float*   pm_b2 = (const float*)d_in[8];
    const float*   am_w1 = (const float*)d_in[9];
    const float*   am_b1 = (const float*)d_in[10];
    const float*   am_w2 = (const float*)d_in[11];
    // am_w2 bias (d_in[12]) cancels in softmax -> unused
    float* out = (float*)d_out;
    const int n = in_sizes[0] / DIM;

    uint8_t* ws = (uint8_t*)d_ws;
    float*    qf   = (float*)ws;                                  // n*64 f32
    uint16_t* kvp  = (uint16_t*)(ws + (size_t)n * 256);           // n*128 bf16
    uint16_t* w1p  = (uint16_t*)(ws + (size_t)n * 512);           // 16384 bf16
    uint16_t* w2p  = w1p + 16384;                                 // 16384 bf16
    uint16_t* pw2p = w2p + 16384;                                 // 4096 bf16

    qkv_kernel<<<(n * 48 + 255) / 256, 256, 0, stream>>>(x, wqkv, qf, kvp, n);
    wpack_kernel<<<144, 256, 0, stream>>>(am_w1, am_w2, pm_w2, w1p, w2p, pw2p);
    ptl_main<<<512, 256, 0, stream>>>(pos, aidx, mask, pm_w1, pm_b1, pm_b2, am_b1,
                                      qf, kvp, w1p, w2p, pw2p, out, n);
}